// Round 5
// baseline (250.744 us; speedup 1.0000x reference)
//
#include <hip/hip_runtime.h>

// Problem constants (match reference setup_inputs)
#define BSZ   1024
#define NSZ   131072
#define DSZ   256
#define NC    8192
#define TEMPR 0.05f
#define GRID  256        // == #CUs -> 1 block/CU, all co-resident (64KB LDS < 160KB)
#define TPB   512        // 8 waves/block

typedef float f32x4_t __attribute__((ext_vector_type(4)));
typedef int   i32x4_t __attribute__((ext_vector_type(4)));

__device__ __forceinline__ unsigned short f2bf(float f) {
  unsigned u = __float_as_uint(f);
  u += 0x7fffu + ((u >> 16) & 1u);
  return (unsigned short)(u >> 16);
}

// Grid-wide barrier: monotonic counter, agent-scope acq/rel (handles cross-XCD
// L2 visibility via the release wbL2 / acquire invL2 the compiler emits).
// Requires all GRID blocks co-resident: GRID=256=#CUs, 1 block/CU. Counter is
// zeroed by a memset node at the start of each graph replay.
__device__ __forceinline__ void gsync(int* bar, int target) {
  __syncthreads();
  if (threadIdx.x == 0) {
    __hip_atomic_fetch_add(bar, 1, __ATOMIC_ACQ_REL, __HIP_MEMORY_SCOPE_AGENT);
    while (__hip_atomic_load(bar, __ATOMIC_ACQUIRE, __HIP_MEMORY_SCOPE_AGENT) < target)
      __builtin_amdgcn_s_sleep(8);
  }
  __syncthreads();
}

// Zeroed region: cnt (8192 int) + sumexp (1024 f32) = 9216 words = 2304 float4
#define ZERO_F4_COUNT 2304

__global__ __launch_bounds__(TPB) void k_fused(const float* __restrict__ in,
                                               const float* __restrict__ feat,
                                               const int* __restrict__ indexes,
                                               const int* __restrict__ labels,
                                               float* __restrict__ inorm,
                                               unsigned short* __restrict__ anorm,
                                               float* __restrict__ csum,
                                               unsigned short* __restrict__ cmean,
                                               float* __restrict__ nums,
                                               int* __restrict__ offs,
                                               int* __restrict__ cursor,
                                               int* __restrict__ bucket,
                                               int* __restrict__ cnt,
                                               float* __restrict__ sumexp,
                                               int* __restrict__ bar,
                                               float* __restrict__ out) {
  __shared__ __align__(16) unsigned short a_lds[64 * 256];   // 32 KB (aliased by scan/gather)
  __shared__ __align__(16) unsigned short b_lds[64 * 256];   // 32 KB

  const int tid  = threadIdx.x;
  const int gid  = blockIdx.x * TPB + tid;      // 0..131071 (== NSZ)
  const int lane = tid & 63;
  const int wv   = tid >> 6;                    // 0..7

  // ---------------- P1: zero accumulators + normalize inputs ----------------
  if (gid < ZERO_F4_COUNT) reinterpret_cast<float4*>(cnt)[gid] = make_float4(0.f, 0.f, 0.f, 0.f);
  if (gid == 0) out[0] = 0.f;
  {
    int wid = gid >> 6;                         // 0..2047; rows 0..1023 active
    if (wid < BSZ) {
      float4 v = reinterpret_cast<const float4*>(in)[wid * 64 + lane];
      float ss = v.x * v.x + v.y * v.y + v.z * v.z + v.w * v.w;
#pragma unroll
      for (int off = 32; off; off >>= 1) ss += __shfl_xor(ss, off);
      float rn = 1.f / fmaxf(sqrtf(ss), 1e-12f);
      float4 o = make_float4(v.x * rn, v.y * rn, v.z * rn, v.w * rn);
      reinterpret_cast<float4*>(inorm)[wid * 64 + lane] = o;
      ushort4 ob = make_ushort4(f2bf(o.x), f2bf(o.y), f2bf(o.z), f2bf(o.w));
      reinterpret_cast<ushort4*>(anorm)[wid * 64 + lane] = ob;
    }
  }
  gsync(bar, 1 * GRID);

  // ---------------- P2: label histogram ----------------
  atomicAdd(&cnt[labels[gid]], 1);
  gsync(bar, 2 * GRID);

  // ---------------- P3: exclusive scan (block 0 only) ----------------
  if (blockIdx.x == 0) {
    int* tot = (int*)a_lds;
    int v[16];
    int s = 0;
#pragma unroll
    for (int j = 0; j < 16; j++) { v[j] = cnt[tid * 16 + j]; s += v[j]; }
    tot[tid] = s;
    __syncthreads();
    for (int off = 1; off < TPB; off <<= 1) {
      int x = (tid >= off) ? tot[tid - off] : 0;
      __syncthreads();
      tot[tid] += x;
      __syncthreads();
    }
    int run = tot[tid] - s;
#pragma unroll
    for (int j = 0; j < 16; j++) {
      int c = tid * 16 + j;
      offs[c]   = run;
      cursor[c] = run;
      nums[c]   = (float)v[j];
      run += v[j];
    }
  }
  gsync(bar, 3 * GRID);

  // ---------------- P4: bucket fill ----------------
  {
    int p = atomicAdd(&cursor[labels[gid]], 1);
    bucket[p] = gid;
  }
  gsync(bar, 4 * GRID);

  // ---------------- P5: gather + normalize + cluster-sum ----------------
  // Block handles 32 clusters; two 4-wave groups work 2 clusters per iteration.
  {
    float4* part = (float4*)a_lds;              // 2 groups x 192 float4 = 6 KB
    int g  = wv >> 2;                           // group 0/1
    int sw = wv & 3;                            // sub-wave in group
    for (int k = 0; k < 16; ++k) {
      int c = blockIdx.x * 32 + k * 2 + g;
      int o = offs[c];
      int n = cnt[c];
      int j = sw + 4 * lane;                    // bucket entry this lane preloads
      int myidx = (j < n) ? bucket[o + j] : 0;
      float4 acc = make_float4(0.f, 0.f, 0.f, 0.f);
      int iters = (n - sw + 3) >> 2;
      float4 v;
      if (iters > 0) {
        int s0 = __shfl(myidx, 0);
        v = reinterpret_cast<const float4*>(feat)[(size_t)s0 * 64 + lane];
      }
      for (int t = 0; t < iters; ++t) {
        float4 cur = v;
        if (t + 1 < iters) {                    // prefetch next row
          int sn = __shfl(myidx, t + 1);
          v = reinterpret_cast<const float4*>(feat)[(size_t)sn * 64 + lane];
        }
        float ss = cur.x * cur.x + cur.y * cur.y + cur.z * cur.z + cur.w * cur.w;
#pragma unroll
        for (int off = 32; off; off >>= 1) ss += __shfl_xor(ss, off);
        float rn = 1.f / fmaxf(sqrtf(ss), 1e-12f);
        acc.x += cur.x * rn; acc.y += cur.y * rn; acc.z += cur.z * rn; acc.w += cur.w * rn;
      }
      __syncthreads();                          // protect part[] reuse
      if (sw > 0) part[g * 192 + (sw - 1) * 64 + lane] = acc;
      __syncthreads();
      if (sw == 0) {
        float4 p1 = part[g * 192 + lane], p2 = part[g * 192 + 64 + lane], p3 = part[g * 192 + 128 + lane];
        acc.x += p1.x + p2.x + p3.x;
        acc.y += p1.y + p2.y + p3.y;
        acc.z += p1.z + p2.z + p3.z;
        acc.w += p1.w + p2.w + p3.w;
        reinterpret_cast<float4*>(csum)[c * 64 + lane] = acc;
        float den = n > 0 ? (float)n : 1.f;
        float sc = 1.f / (TEMPR * den);
        ushort4 ob = make_ushort4(f2bf(acc.x * sc), f2bf(acc.y * sc),
                                  f2bf(acc.z * sc), f2bf(acc.w * sc));
        reinterpret_cast<ushort4*>(cmean)[c * 64 + lane] = ob;
      }
    }
  }
  gsync(bar, 5 * GRID);

  // ---------------- P6: bf16 MFMA GEMM + fused exp-sum epilogue ----------------
  // Block: A-panel bm0 = (blk&15)*64 staged once; 8 B-tiles of 64 cols.
  // 8 waves: rows quadrant (wv&3)*16, col half (wv>>2)*32, 2 frags each.
  {
    const int bm0 = (blockIdx.x & 15) * 64;
    const int col16 = lane & 15;
    const int khalf = lane >> 4;
    const int rq = wv & 3;                      // row quadrant
    const int ch = wv >> 2;                     // col half (0/1)

    const uint4* Ag = reinterpret_cast<const uint4*>(anorm) + (size_t)bm0 * 32;
#pragma unroll
    for (int i = 0; i < 4; i++) {               // stage A: 2048 uint4
      int l = tid + i * TPB;
      int row = l >> 5, c8 = l & 31;
      int e = (row << 8) + (c8 << 3);
      e ^= (row & 7) << 3;
      *reinterpret_cast<uint4*>(&a_lds[e]) = Ag[l];
    }

    for (int j = 0; j < 8; j++) {
      const int bn0 = ((blockIdx.x >> 4) * 8 + j) * 64;
      const uint4* Bg = reinterpret_cast<const uint4*>(cmean) + (size_t)bn0 * 32;
      __syncthreads();                          // b_lds reuse guard (also covers A-stage on j==0 path begin)
#pragma unroll
      for (int i = 0; i < 4; i++) {             // stage B: 2048 uint4
        int l = tid + i * TPB;
        int row = l >> 5, c8 = l & 31;
        int e = (row << 8) + (c8 << 3);
        e ^= (row & 7) << 3;
        *reinterpret_cast<uint4*>(&b_lds[e]) = Bg[l];
      }
      __syncthreads();

      f32x4_t acc[2] = {};
      const int arow = rq * 16 + col16;
#pragma unroll
      for (int k0 = 0; k0 < 256; k0 += 32) {
        const int kk = k0 + khalf * 8;
        int ea = (arow << 8) + kk;
        ea ^= (arow & 7) << 3;
        i32x4_t af = *reinterpret_cast<const i32x4_t*>(&a_lds[ea]);
#pragma unroll
        for (int n = 0; n < 2; n++) {
          const int brow = ch * 32 + n * 16 + col16;
          int eb = (brow << 8) + kk;
          eb ^= (brow & 7) << 3;
          i32x4_t bf = *reinterpret_cast<const i32x4_t*>(&b_lds[eb]);
          asm("v_mfma_f32_16x16x32_bf16 %0, %1, %2, %0" : "+v"(acc[n]) : "v"(af), "v"(bf));
        }
      }

      float s0 = 0.f, s1 = 0.f, s2 = 0.f, s3 = 0.f;
#pragma unroll
      for (int n = 0; n < 2; n++) {
        int gc = bn0 + ch * 32 + n * 16 + col16;
        float msk = nums[gc] > 0.f ? 1.f : 0.f;
        s0 += msk * __expf(acc[n][0]);
        s1 += msk * __expf(acc[n][1]);
        s2 += msk * __expf(acc[n][2]);
        s3 += msk * __expf(acc[n][3]);
      }
#pragma unroll
      for (int off = 1; off < 16; off <<= 1) {
        s0 += __shfl_xor(s0, off);
        s1 += __shfl_xor(s1, off);
        s2 += __shfl_xor(s2, off);
        s3 += __shfl_xor(s3, off);
      }
      if (col16 == 0) {
        int r = bm0 + rq * 16 + khalf * 4;
        atomicAdd(&sumexp[r + 0], s0);
        atomicAdd(&sumexp[r + 1], s1);
        atomicAdd(&sumexp[r + 2], s2);
        atomicAdd(&sumexp[r + 3], s3);
      }
    }
  }
  gsync(bar, 6 * GRID);

  // ---------------- P7: per-sample target logit + loss ----------------
  {
    int w = gid >> 6;
    if (w < BSZ) {
      int t = labels[indexes[w]];
      float4 x = reinterpret_cast<const float4*>(inorm)[w * 64 + lane];
      float4 c = reinterpret_cast<const float4*>(csum)[t * 64 + lane];
      float d = x.x * c.x + x.y * c.y + x.z * c.z + x.w * c.w;
#pragma unroll
      for (int off = 32; off; off >>= 1) d += __shfl_xor(d, off);
      if (lane == 0) {
        float den = nums[t];
        den = den > 0.f ? den : 1.f;
        float simt = d / (TEMPR * den);
        float p = __expf(simt) / (sumexp[w] + 1e-6f);
        atomicAdd(out, -logf(p + 1e-6f) * (1.0f / (float)BSZ));
      }
    }
  }
}

// ---------- workspace layout (bytes) ----------
#define OFF_INORM   0u                           // 1024*256*4   = 1,048,576
#define OFF_CSUM    1048576u                     // 8192*256*4   = 8,388,608
#define OFF_NUMS    (OFF_CSUM + 8388608u)        // 8192*4       = 32,768
#define OFF_ANORM   (OFF_NUMS + 32768u)          // 1024*256*2   = 524,288
#define OFF_CMEAN   (OFF_ANORM + 524288u)        // 8192*256*2   = 4,194,304
#define OFF_OFFS    (OFF_CMEAN + 4194304u)       // 8192*4       = 32,768
#define OFF_CURSOR  (OFF_OFFS + 32768u)          // 8192*4       = 32,768
#define OFF_BUCKET  (OFF_CURSOR + 32768u)        // 131072*4     = 524,288
// ---- zeroed-in-P1 region (contiguous): cnt, sumexp ----
#define OFF_CNT     (OFF_BUCKET + 524288u)       // 8192*4       = 32,768
#define OFF_SUMEXP  (OFF_CNT + 32768u)           // 1024*4       = 4,096
#define OFF_BAR     (OFF_SUMEXP + 4096u)         // 64 (memset each replay)

extern "C" void kernel_launch(void* const* d_in, const int* in_sizes, int n_in,
                              void* d_out, int out_size, void* d_ws, size_t ws_size,
                              hipStream_t stream) {
  const float* inputs   = (const float*)d_in[0];
  const float* features = (const float*)d_in[1];
  const int*   indexes  = (const int*)d_in[2];
  const int*   labels   = (const int*)d_in[3];
  float* out = (float*)d_out;

  char* ws = (char*)d_ws;
  float*          inorm   = (float*)(ws + OFF_INORM);
  float*          csum    = (float*)(ws + OFF_CSUM);
  float*          nums    = (float*)(ws + OFF_NUMS);
  unsigned short* anorm   = (unsigned short*)(ws + OFF_ANORM);
  unsigned short* cmean   = (unsigned short*)(ws + OFF_CMEAN);
  int*            offs    = (int*)(ws + OFF_OFFS);
  int*            cursor  = (int*)(ws + OFF_CURSOR);
  int*            bucket  = (int*)(ws + OFF_BUCKET);
  int*            cnt     = (int*)(ws + OFF_CNT);
  float*          sumexp  = (float*)(ws + OFF_SUMEXP);
  int*            bar     = (int*)(ws + OFF_BAR);

  hipMemsetAsync(bar, 0, 64, stream);
  k_fused<<<GRID, TPB, 0, stream>>>(inputs, features, indexes, labels,
                                    inorm, anorm, csum, cmean, nums,
                                    offs, cursor, bucket, cnt, sumexp, bar, out);
}

// Round 6
// 92.011 us; speedup vs baseline: 2.7251x; 2.7251x over previous
//
#include <hip/hip_runtime.h>

// Problem constants (match reference setup_inputs)
#define BSZ   1024
#define NSZ   131072
#define DSZ   256
#define NC    8192
#define TEMPR 0.05f

typedef float f32x4_t __attribute__((ext_vector_type(4)));
typedef int   i32x4_t __attribute__((ext_vector_type(4)));

__device__ __forceinline__ unsigned short f2bf(float f) {
  unsigned u = __float_as_uint(f);
  u += 0x7fffu + ((u >> 16) & 1u);
  return (unsigned short)(u >> 16);
}

// Zeroed region: cnt (8192 int) + sumexp (1024 f32) = 9216 words = 2304 float4
#define ZERO_F4_COUNT 2304

// ---------- kernel 1: L2-normalize input rows -> bf16; zero cnt+sumexp ----------
__global__ __launch_bounds__(256) void k_norm_inputs(const float* __restrict__ in,
                                                     unsigned short* __restrict__ anorm,
                                                     float4* __restrict__ zero_region) {
  int gid  = blockIdx.x * 256 + threadIdx.x;     // 0..65535
  if (gid < ZERO_F4_COUNT) zero_region[gid] = make_float4(0.f, 0.f, 0.f, 0.f);
  int wid  = gid >> 6;                            // row 0..1023
  int lane = threadIdx.x & 63;
  float4 v = reinterpret_cast<const float4*>(in)[wid * 64 + lane];
  float ss = v.x * v.x + v.y * v.y + v.z * v.z + v.w * v.w;
#pragma unroll
  for (int off = 32; off; off >>= 1) ss += __shfl_xor(ss, off);
  float rn = 1.f / fmaxf(sqrtf(ss), 1e-12f);
  ushort4 ob = make_ushort4(f2bf(v.x * rn), f2bf(v.y * rn), f2bf(v.z * rn), f2bf(v.w * rn));
  reinterpret_cast<ushort4*>(anorm)[wid * 64 + lane] = ob;
}

// ---------- kernel 2: label histogram ----------
__global__ __launch_bounds__(256) void k_hist(const int* __restrict__ labels,
                                              int* __restrict__ cnt) {
  int i = blockIdx.x * 256 + threadIdx.x;
  atomicAdd(&cnt[labels[i]], 1);
}

// ---------- kernel 3: exclusive scan over 8192 counts (1 block, shfl-based) ----------
__global__ __launch_bounds__(1024) void k_scan(const int* __restrict__ cnt,
                                               int* __restrict__ offs,
                                               int* __restrict__ cursor,
                                               float* __restrict__ nums) {
  __shared__ int wt[16];
  int tid  = threadIdx.x;
  int lane = tid & 63, wv = tid >> 6;
  int v[8];
  int s = 0;
#pragma unroll
  for (int j = 0; j < 8; j++) { v[j] = cnt[tid * 8 + j]; s += v[j]; }
  int incl = s;
#pragma unroll
  for (int off = 1; off < 64; off <<= 1) {
    int x = __shfl_up(incl, off);
    if (lane >= off) incl += x;
  }
  if (lane == 63) wt[wv] = incl;
  __syncthreads();
  if (tid < 16) {
    int own = wt[tid];
    int wi = own;
#pragma unroll
    for (int off = 1; off < 16; off <<= 1) {
      int x = __shfl_up(wi, off);
      if (tid >= off) wi += x;
    }
    wt[tid] = wi - own;                 // exclusive wave offset
  }
  __syncthreads();
  int run = wt[wv] + incl - s;          // exclusive start for this thread's chunk
#pragma unroll
  for (int j = 0; j < 8; j++) {
    int c = tid * 8 + j;
    offs[c]   = run;
    cursor[c] = run;
    nums[c]   = (float)v[j];
    run += v[j];
  }
}

// ---------- kernel 4: fill per-cluster buckets with sample indices ----------
__global__ __launch_bounds__(256) void k_fill(const int* __restrict__ labels,
                                              int* __restrict__ cursor,
                                              int* __restrict__ bucket) {
  int i = blockIdx.x * 256 + threadIdx.x;
  int p = atomicAdd(&cursor[labels[i]], 1);
  bucket[p] = i;
}

// ---------- kernel 5: gather members, normalize rows, sum -> cmean bf16 ----------
// One block (4 waves) per cluster; wave wv handles members wv, wv+4, ...
__global__ __launch_bounds__(256) void k_gather_sum(const float* __restrict__ feat,
                                                    const int* __restrict__ bucket,
                                                    const int* __restrict__ offs,
                                                    const int* __restrict__ cnt,
                                                    unsigned short* __restrict__ cmean) {
  __shared__ float4 part[192];
  int c    = blockIdx.x;
  int lane = threadIdx.x & 63;
  int wv   = threadIdx.x >> 6;
  int o = offs[c];
  int n = cnt[c];
  int j = wv + 4 * lane;
  int myidx = (j < n) ? bucket[o + j] : 0;
  float4 acc = make_float4(0.f, 0.f, 0.f, 0.f);
  int iters = (n - wv + 3) >> 2;
  float4 v;
  if (iters > 0) {
    int s0 = __shfl(myidx, 0);
    v = reinterpret_cast<const float4*>(feat)[(size_t)s0 * 64 + lane];
  }
  for (int t = 0; t < iters; ++t) {
    float4 cur = v;
    if (t + 1 < iters) {
      int sn = __shfl(myidx, t + 1);
      v = reinterpret_cast<const float4*>(feat)[(size_t)sn * 64 + lane];
    }
    float ss = cur.x * cur.x + cur.y * cur.y + cur.z * cur.z + cur.w * cur.w;
#pragma unroll
    for (int off = 32; off; off >>= 1) ss += __shfl_xor(ss, off);
    float rn = 1.f / fmaxf(sqrtf(ss), 1e-12f);
    acc.x += cur.x * rn; acc.y += cur.y * rn; acc.z += cur.z * rn; acc.w += cur.w * rn;
  }
  if (wv > 0) part[(wv - 1) * 64 + lane] = acc;
  __syncthreads();
  if (wv == 0) {
    float4 p1 = part[lane], p2 = part[64 + lane], p3 = part[128 + lane];
    acc.x += p1.x + p2.x + p3.x;
    acc.y += p1.y + p2.y + p3.y;
    acc.z += p1.z + p2.z + p3.z;
    acc.w += p1.w + p2.w + p3.w;
    float den = n > 0 ? (float)n : 1.f;
    float sc = 1.f / (TEMPR * den);
    ushort4 ob = make_ushort4(f2bf(acc.x * sc), f2bf(acc.y * sc),
                              f2bf(acc.z * sc), f2bf(acc.w * sc));
    reinterpret_cast<ushort4*>(cmean)[c * 64 + lane] = ob;
  }
}

// ---------- kernel 6: bf16 MFMA GEMM + fused exp-sum + target-logit capture ----------
// A: anorm [1024][256] bf16; Bt: cmean [8192][256] bf16. Tile 64x64, 4 waves.
__global__ __launch_bounds__(256) void k_gemm_expsum(const unsigned short* __restrict__ A,
                                                     const unsigned short* __restrict__ Bt,
                                                     const float* __restrict__ nums,
                                                     const int* __restrict__ indexes,
                                                     const int* __restrict__ labels,
                                                     float* __restrict__ sumexp,
                                                     float* __restrict__ tlogit) {
  __shared__ __align__(16) unsigned short a_lds[64 * 256];
  __shared__ __align__(16) unsigned short b_lds[64 * 256];
  __shared__ int t_lds[64];
  const int bn0 = blockIdx.x * 64;
  const int bm0 = blockIdx.y * 64;

  if (threadIdx.x < 64) t_lds[threadIdx.x] = labels[indexes[bm0 + threadIdx.x]];

  const uint4* Ag = reinterpret_cast<const uint4*>(A) + (size_t)bm0 * 32;
  const uint4* Bg = reinterpret_cast<const uint4*>(Bt) + (size_t)bn0 * 32;
#pragma unroll
  for (int i = 0; i < 8; i++) {
    int l = threadIdx.x + i * 256;
    int row = l >> 5, c8 = l & 31;
    int e = (row << 8) + (c8 << 3);
    e ^= (row & 7) << 3;                 // XOR swizzle -> conflict-free reads
    *reinterpret_cast<uint4*>(&a_lds[e]) = Ag[l];
    *reinterpret_cast<uint4*>(&b_lds[e]) = Bg[l];
  }
  __syncthreads();

  const int lane  = threadIdx.x & 63;
  const int w     = threadIdx.x >> 6;
  const int col16 = lane & 15;
  const int khalf = lane >> 4;

  f32x4_t acc[4] = {};
  const int arow = w * 16 + col16;
#pragma unroll
  for (int k0 = 0; k0 < 256; k0 += 32) {
    const int kk = k0 + khalf * 8;
    int ea = (arow << 8) + kk;
    ea ^= (arow & 7) << 3;
    i32x4_t af = *reinterpret_cast<const i32x4_t*>(&a_lds[ea]);
#pragma unroll
    for (int n = 0; n < 4; n++) {
      const int brow = n * 16 + col16;
      int eb = (brow << 8) + kk;
      eb ^= (brow & 7) << 3;
      i32x4_t bf = *reinterpret_cast<const i32x4_t*>(&b_lds[eb]);
      asm("v_mfma_f32_16x16x32_bf16 %0, %1, %2, %0" : "+v"(acc[n]) : "v"(af), "v"(bf));
    }
  }

  // target-logit capture: exactly one (row, col) match grid-wide per row
  const int r0 = w * 16 + khalf * 4;
#pragma unroll
  for (int n = 0; n < 4; n++) {
    int gc = bn0 + n * 16 + col16;
#pragma unroll
    for (int i = 0; i < 4; i++) {
      if (t_lds[r0 + i] == gc) tlogit[bm0 + r0 + i] = acc[n][i];
    }
  }

  float s0 = 0.f, s1 = 0.f, s2 = 0.f, s3 = 0.f;
#pragma unroll
  for (int n = 0; n < 4; n++) {
    int gc = bn0 + n * 16 + col16;
    float msk = nums[gc] > 0.f ? 1.f : 0.f;
    s0 += msk * __expf(acc[n][0]);
    s1 += msk * __expf(acc[n][1]);
    s2 += msk * __expf(acc[n][2]);
    s3 += msk * __expf(acc[n][3]);
  }
#pragma unroll
  for (int off = 1; off < 16; off <<= 1) {
    s0 += __shfl_xor(s0, off);
    s1 += __shfl_xor(s1, off);
    s2 += __shfl_xor(s2, off);
    s3 += __shfl_xor(s3, off);
  }
  if (col16 == 0) {
    int r = bm0 + w * 16 + khalf * 4;
    atomicAdd(&sumexp[r + 0], s0);
    atomicAdd(&sumexp[r + 1], s1);
    atomicAdd(&sumexp[r + 2], s2);
    atomicAdd(&sumexp[r + 3], s3);
  }
}

// ---------- kernel 7: loss finalize (1 block, no atomics) ----------
__global__ __launch_bounds__(1024) void k_loss(const float* __restrict__ tlogit,
                                               const float* __restrict__ sumexp,
                                               float* __restrict__ out) {
  __shared__ float ws[16];
  int tid = threadIdx.x;
  float p = __expf(tlogit[tid]) / (sumexp[tid] + 1e-6f);
  float lp = logf(p + 1e-6f);
#pragma unroll
  for (int off = 32; off; off >>= 1) lp += __shfl_xor(lp, off);
  if ((tid & 63) == 0) ws[tid >> 6] = lp;
  __syncthreads();
  if (tid < 16) {
    float x = ws[tid];
#pragma unroll
    for (int off = 8; off; off >>= 1) x += __shfl_xor(x, off);
    if (tid == 0) out[0] = -x * (1.0f / (float)BSZ);
  }
}

// ---------- workspace layout (bytes) ----------
#define OFF_ANORM   0u                           // 1024*256*2   = 524,288
#define OFF_CMEAN   524288u                      // 8192*256*2   = 4,194,304
#define OFF_NUMS    (OFF_CMEAN + 4194304u)       // 8192*4       = 32,768
#define OFF_OFFS    (OFF_NUMS + 32768u)          // 8192*4       = 32,768
#define OFF_CURSOR  (OFF_OFFS + 32768u)          // 8192*4       = 32,768
#define OFF_BUCKET  (OFF_CURSOR + 32768u)        // 131072*4     = 524,288
// ---- zeroed-in-K1 region (contiguous): cnt, sumexp ----
#define OFF_CNT     (OFF_BUCKET + 524288u)       // 8192*4       = 32,768
#define OFF_SUMEXP  (OFF_CNT + 32768u)           // 1024*4       = 4,096
#define OFF_TLOGIT  (OFF_SUMEXP + 4096u)         // 1024*4       = 4,096

extern "C" void kernel_launch(void* const* d_in, const int* in_sizes, int n_in,
                              void* d_out, int out_size, void* d_ws, size_t ws_size,
                              hipStream_t stream) {
  const float* inputs   = (const float*)d_in[0];
  const float* features = (const float*)d_in[1];
  const int*   indexes  = (const int*)d_in[2];
  const int*   labels   = (const int*)d_in[3];
  float* out = (float*)d_out;

  char* ws = (char*)d_ws;
  unsigned short* anorm   = (unsigned short*)(ws + OFF_ANORM);
  unsigned short* cmean   = (unsigned short*)(ws + OFF_CMEAN);
  float*          nums    = (float*)(ws + OFF_NUMS);
  int*            offs    = (int*)(ws + OFF_OFFS);
  int*            cursor  = (int*)(ws + OFF_CURSOR);
  int*            bucket  = (int*)(ws + OFF_BUCKET);
  int*            cnt     = (int*)(ws + OFF_CNT);
  float*          sumexp  = (float*)(ws + OFF_SUMEXP);
  float*          tlogit  = (float*)(ws + OFF_TLOGIT);

  k_norm_inputs<<<256, 256, 0, stream>>>(inputs, anorm, (float4*)(ws + OFF_CNT));
  k_hist<<<NSZ / 256, 256, 0, stream>>>(labels, cnt);
  k_scan<<<1, 1024, 0, stream>>>(cnt, offs, cursor, nums);
  k_fill<<<NSZ / 256, 256, 0, stream>>>(labels, cursor, bucket);
  k_gather_sum<<<NC, 256, 0, stream>>>(features, bucket, offs, cnt, cmean);
  k_gemm_expsum<<<dim3(NC / 64, BSZ / 64), 256, 0, stream>>>(anorm, cmean, nums,
                                                             indexes, labels, sumexp, tlogit);
  k_loss<<<1, 1024, 0, stream>>>(tlogit, sumexp, out);
}